// Round 2
// baseline (2585.766 us; speedup 1.0000x reference)
//
#include <hip/hip_runtime.h>

// LlamaAttentionFused: B=2, S=2048, D=4096, H=32, HD=128, fp32 in/out.
// Strategy: fp16 MFMA (16x16x32) with fp32 accumulation everywhere.
// GEMMs use the m97 structure: 128x128 tile, BK=32, 4 waves (2x2), 4x4
// frags/wave, global_load_lds width=16 into linear LDS.
// ws layout (160 MiB needed):
//   [0,32M)    x16  (fp16 x)          -- reused as attention output a16
//   [32,64M)   wT   (fp16 transposed weight, reused for wq/wk/wv/wo)
//   [64,96M)   q16  (post-RoPE Q, fp16, [b*S+s][h*HD+hd])
//   [96,128M)  k16  (post-RoPE K)
//   [128,160M) vT16 (V transposed per head: [(b*H+h)*HD+hd][S])

typedef _Float16 f16;
typedef _Float16 f16x8 __attribute__((ext_vector_type(8)));
typedef _Float16 f16x4 __attribute__((ext_vector_type(4)));
typedef float    f32x4 __attribute__((ext_vector_type(4)));

#define MFMA16(a, b, c) __builtin_amdgcn_mfma_f32_16x16x32_f16(a, b, c, 0, 0, 0)

// global -> LDS direct, 16B per lane. LDS dest = wave-uniform base + lane*16.
// AS casts go through integers: AS(3) is 32-bit on AMDGPU, so truncating the
// generic pointer yields the LDS offset (CK's cast pattern).
#define GLOAD16(gp, lp)                                                        \
    __builtin_amdgcn_global_load_lds(                                          \
        (const __attribute__((address_space(1))) void*)(uintptr_t)(gp),        \
        (__attribute__((address_space(3))) void*)(uint32_t)(uintptr_t)(lp),    \
        16, 0, 0)

constexpr int SEQ = 2048, DIM = 4096, NH = 32, HD = 128;

// ---------------- x fp32 -> fp16 (vectorized, exact grid) ----------------
__global__ void cvt_x_kernel(const float* __restrict__ x, f16* __restrict__ o) {
    int i = blockIdx.x * blockDim.x + threadIdx.x;   // 8 elems per thread
    const float4* p = (const float4*)x;
    float4 a = p[2 * i], b = p[2 * i + 1];
    f16x8 v = {(f16)a.x, (f16)a.y, (f16)a.z, (f16)a.w,
               (f16)b.x, (f16)b.y, (f16)b.z, (f16)b.w};
    ((f16x8*)o)[i] = v;
}

// ------------- w [K][N] f32 -> wT [N][K] f16 (LDS tile transpose) -------------
__global__ void cvt_wT_kernel(const float* __restrict__ w, f16* __restrict__ wT) {
    __shared__ float t[64][65];
    const int c0 = blockIdx.x * 64, r0 = blockIdx.y * 64;
    const int tr = threadIdx.x >> 4, tc = threadIdx.x & 15;
#pragma unroll
    for (int p = 0; p < 4; ++p) {
        int r = p * 16 + tr;
        float4 v = *(const float4*)&w[(size_t)(r0 + r) * DIM + c0 + tc * 4];
        t[tc * 4 + 0][r] = v.x; t[tc * 4 + 1][r] = v.y;
        t[tc * 4 + 2][r] = v.z; t[tc * 4 + 3][r] = v.w;
    }
    __syncthreads();
#pragma unroll
    for (int p = 0; p < 4; ++p) {
        int n = p * 16 + tr;
        f16x4 v = {(f16)t[n][tc * 4 + 0], (f16)t[n][tc * 4 + 1],
                   (f16)t[n][tc * 4 + 2], (f16)t[n][tc * 4 + 3]};
        *(f16x4*)&wT[(size_t)(c0 + n) * DIM + r0 + tc * 4] = v;
    }
}

// ---------------- GEMM: C[4096x4096] = A[4096x4096] * BT^T ----------------
// A row-major [M][K] fp16, BT row-major [N][K] fp16.
// EPI: 0 = RoPE fp16 out, 1 = per-head V-transpose fp16 out, 2 = fp32 out.
union GemmLds {
    struct { f16 As[128][32]; f16 Bs[128][32]; } st;  // 16 KiB, LINEAR (global_load_lds dest)
    float C[64][133];                                  // 34 KiB epilogue bounce (64-row passes)
};

template <int EPI>
__launch_bounds__(256, 2)
__global__ void gemm_kernel(const f16* __restrict__ A, const f16* __restrict__ BT,
                            void* __restrict__ OutP,
                            const float* __restrict__ fc, const float* __restrict__ fs) {
    __shared__ GemmLds lds;
    // XCD-aware bijective swizzle: 1024 blocks, 1024 % 8 == 0.
    const int bid = blockIdx.x;
    const int swz = (bid & 7) * 128 + (bid >> 3);
    const int n0 = (swz & 31) * 128, m0 = (swz >> 5) * 128;
    const int tid = threadIdx.x;
    const int lane = tid & 63, w = tid >> 6;
    const int wr = w >> 1, wc = w & 1;           // wave grid 2x2
    const int lrow = lane & 15, lk = lane >> 4;  // frag row, k-group

    // staging addresses: thread tid covers LDS bytes [tid*16, tid*16+16)
    // of each 64-row half-tile -> row tid>>2, f16 col (tid&3)*8.
    const int srow = tid >> 2, scol = (tid & 3) * 8;
    const f16* gA = A + (size_t)(m0 + srow) * DIM + scol;
    const f16* gB = BT + (size_t)(n0 + srow) * DIM + scol;
    f16* lA = &lds.st.As[0][0] + w * 512;   // wave-uniform (w*1024 bytes)
    f16* lB = &lds.st.Bs[0][0] + w * 512;

    f32x4 acc[4][4] = {};

    for (int k0 = 0; k0 < DIM; k0 += 32) {
        __syncthreads();  // previous iteration's frag reads complete
        GLOAD16(gA + k0, lA);
        GLOAD16(gA + k0 + (size_t)64 * DIM, lA + 64 * 32);
        GLOAD16(gB + k0, lB);
        GLOAD16(gB + k0 + (size_t)64 * DIM, lB + 64 * 32);
        __syncthreads();  // drains vmcnt: tile visible to all waves
        f16x8 af[4], bf[4];
#pragma unroll
        for (int i = 0; i < 4; ++i) af[i] = *(const f16x8*)&lds.st.As[wr * 64 + i * 16 + lrow][lk * 8];
#pragma unroll
        for (int j = 0; j < 4; ++j) bf[j] = *(const f16x8*)&lds.st.Bs[wc * 64 + j * 16 + lrow][lk * 8];
#pragma unroll
        for (int i = 0; i < 4; ++i)
#pragma unroll
            for (int j = 0; j < 4; ++j)
                acc[i][j] = MFMA16(af[i], bf[j], acc[i][j]);
    }

    if constexpr (EPI == 2) {  // fp32 direct store (final @ wo)
        float* Out = (float*)OutP;
#pragma unroll
        for (int i = 0; i < 4; ++i)
#pragma unroll
            for (int j = 0; j < 4; ++j)
#pragma unroll
                for (int r = 0; r < 4; ++r)
                    Out[(size_t)(m0 + wr * 64 + i * 16 + lk * 4 + r) * DIM +
                        n0 + wc * 64 + j * 16 + lrow] = acc[i][j][r];
        return;
    }

    // LDS-bounce epilogues, 64 output rows per pass
    for (int pass = 0; pass < 2; ++pass) {
        __syncthreads();
        if (wr == pass) {
#pragma unroll
            for (int i = 0; i < 4; ++i)
#pragma unroll
                for (int j = 0; j < 4; ++j)
#pragma unroll
                    for (int r = 0; r < 4; ++r)
                        lds.C[i * 16 + lk * 4 + r][wc * 64 + j * 16 + lrow] = acc[i][j][r];
        }
        __syncthreads();
        const int rowbase = m0 + pass * 64;
        if constexpr (EPI == 0) {  // RoPE: N-tile 128 spans exactly one head
            f16* Out = (f16*)OutP;
            for (int it = 0; it < 16; ++it) {
                int idx = it * 256 + tid;
                int r = idx >> 6, p = idx & 63;
                int s = (rowbase + r) & (SEQ - 1);
                float x1 = lds.C[r][p], x2 = lds.C[r][p + 64];
                float c = fc[s * 64 + p], sn = fs[s * 64 + p];
                f16* o = Out + (size_t)(rowbase + r) * DIM + n0;
                o[p]      = (f16)(x1 * c - x2 * sn);
                o[p + 64] = (f16)(x1 * sn + x2 * c);
            }
        } else {  // EPI == 1: V transpose per head -> [(b*NH+h)*HD + hd][SEQ]
            f16* Out = (f16*)OutP;
            const int b = rowbase >> 11, h = n0 >> 7, sbase = rowbase & (SEQ - 1);
            f16* o = Out + ((size_t)(b * NH + h) * HD) * SEQ + sbase;
            for (int rep = 0; rep < 32; ++rep) {
                int hd = rep * 4 + w;
                o[(size_t)hd * SEQ + lane] = (f16)lds.C[lane][hd];
            }
        }
    }
}

// ---------------- Flash attention (causal), fp16 MFMA, fp32 softmax ----------------
// Block: 128 q-rows of one (b,h); 4 waves x 32 rows. KV blocks of 64.
union AttnLds {
    f16 Qs[128][136];                                               // 34.0 KiB (staging only)
    struct { f16 Ks[64][136]; f16 Vs[128][72]; f16 Ps[4][32][72]; } st;  // 53.0 KiB
};

__launch_bounds__(256, 2)
__global__ void attn_kernel(const f16* __restrict__ Q, const f16* __restrict__ K,
                            const f16* __restrict__ VT, f16* __restrict__ O) {
    __shared__ AttnLds lds;
    constexpr float SCALE = 0.08838834764831843f;  // 1/sqrt(128)
    const int q0 = blockIdx.x * 128;
    const int bh = blockIdx.y, b = bh >> 5, h = bh & 31;
    const int tid = threadIdx.x, lane = tid & 63, w = tid >> 6;
    const int lrow = lane & 15, lk = lane >> 4;

    const f16* Qg = Q + (size_t)(b * SEQ + q0) * DIM + h * HD;
    const f16* Kg = K + (size_t)(b * SEQ) * DIM + h * HD;
    const f16* Vg = VT + (size_t)bh * HD * SEQ;

    {  // stage Q tile 128x128
        int r = tid >> 4, c8 = (tid & 15) * 8;
#pragma unroll
        for (int p = 0; p < 8; ++p)
            *(f16x8*)&lds.Qs[p * 16 + r][c8] = *(const f16x8*)&Qg[(size_t)(p * 16 + r) * DIM + c8];
    }
    __syncthreads();
    f16x8 qf[2][4];  // Q frags hoisted to registers: 2 row-frags x 4 k-steps
#pragma unroll
    for (int mi = 0; mi < 2; ++mi)
#pragma unroll
        for (int ks = 0; ks < 4; ++ks)
            qf[mi][ks] = *(const f16x8*)&lds.Qs[w * 32 + mi * 16 + lrow][ks * 32 + lk * 8];

    f32x4 oacc[2][8] = {};
    float rmax[2][4], rsum[2][4];
#pragma unroll
    for (int mi = 0; mi < 2; ++mi)
#pragma unroll
        for (int r = 0; r < 4; ++r) { rmax[mi][r] = -3.0e38f; rsum[mi][r] = 0.f; }

    const int nkv = (q0 >> 6) + 2;  // causal: kv cols up to q0+127
    for (int kv = 0; kv < nkv; ++kv) {
        __syncthreads();  // all waves done reading previous K/V (and Q frags on iter 0)
        {
            int r = tid >> 4, c8 = (tid & 15) * 8;
#pragma unroll
            for (int p = 0; p < 4; ++p)
                *(f16x8*)&lds.st.Ks[p * 16 + r][c8] =
                    *(const f16x8*)&Kg[(size_t)(kv * 64 + p * 16 + r) * DIM + c8];
            int vr = tid >> 3, vc8 = (tid & 7) * 8;
#pragma unroll
            for (int p = 0; p < 4; ++p)
                *(f16x8*)&lds.st.Vs[p * 32 + vr][vc8] =
                    *(const f16x8*)&Vg[(size_t)(p * 32 + vr) * SEQ + kv * 64 + vc8];
        }
        __syncthreads();

        // S = Q K^T : 2x4 frags per wave, k=128 in 4 steps
        f32x4 sacc[2][4] = {};
#pragma unroll
        for (int nj = 0; nj < 4; ++nj)
#pragma unroll
            for (int ks = 0; ks < 4; ++ks) {
                f16x8 kf = *(const f16x8*)&lds.st.Ks[nj * 16 + lrow][ks * 32 + lk * 8];
                sacc[0][nj] = MFMA16(qf[0][ks], kf, sacc[0][nj]);
                sacc[1][nj] = MFMA16(qf[1][ks], kf, sacc[1][nj]);
            }

        const bool need_mask = (kv * 64 + 63) > q0;  // only last two kv blocks
#pragma unroll
        for (int mi = 0; mi < 2; ++mi)
#pragma unroll
            for (int r = 0; r < 4; ++r) {
                float tm = -3.0e38f;
#pragma unroll
                for (int nj = 0; nj < 4; ++nj) {
                    float v = sacc[mi][nj][r] * SCALE;
                    if (need_mask) {
                        int row = q0 + w * 32 + mi * 16 + lk * 4 + r;
                        int col = kv * 64 + nj * 16 + lrow;
                        if (col > row) v = -3.0e38f;
                    }
                    sacc[mi][nj][r] = v;
                    tm = fmaxf(tm, v);
                }
#pragma unroll
                for (int off = 1; off < 16; off <<= 1)
                    tm = fmaxf(tm, __shfl_xor(tm, off, 64));
                float mnew = fmaxf(rmax[mi][r], tm);
                float fac = __expf(rmax[mi][r] - mnew);
                rmax[mi][r] = mnew;
                rsum[mi][r] *= fac;
#pragma unroll
                for (int nh = 0; nh < 8; ++nh) oacc[mi][nh][r] *= fac;
                float ps = 0.f;
#pragma unroll
                for (int nj = 0; nj < 4; ++nj) {
                    float p = __expf(sacc[mi][nj][r] - mnew);
                    sacc[mi][nj][r] = p;
                    ps += p;
                }
#pragma unroll
                for (int off = 1; off < 16; off <<= 1)
                    ps += __shfl_xor(ps, off, 64);
                rsum[mi][r] += ps;
            }

        // P (D-layout) -> per-wave LDS -> A-layout frags.
#pragma unroll
        for (int mi = 0; mi < 2; ++mi)
#pragma unroll
            for (int nj = 0; nj < 4; ++nj)
#pragma unroll
                for (int r = 0; r < 4; ++r)
                    lds.st.Ps[w][mi * 16 + lk * 4 + r][nj * 16 + lrow] = (f16)sacc[mi][nj][r];
        // same-wave write->read ordering: drain LDS queue, pin the schedule
        asm volatile("s_waitcnt lgkmcnt(0)" ::: "memory");
        __builtin_amdgcn_sched_barrier(0);

        // O += P V : k=64 in 2 steps, 8 col-frags (HD=128)
#pragma unroll
        for (int ks = 0; ks < 2; ++ks) {
            f16x8 pf0 = *(const f16x8*)&lds.st.Ps[w][lrow][ks * 32 + lk * 8];
            f16x8 pf1 = *(const f16x8*)&lds.st.Ps[w][16 + lrow][ks * 32 + lk * 8];
#pragma unroll
            for (int nh = 0; nh < 8; ++nh) {
                f16x8 vf = *(const f16x8*)&lds.st.Vs[nh * 16 + lrow][ks * 32 + lk * 8];
                oacc[0][nh] = MFMA16(pf0, vf, oacc[0][nh]);
                oacc[1][nh] = MFMA16(pf1, vf, oacc[1][nh]);
            }
        }
    }

    // epilogue: normalize and store fp16 [b*S+s][h*HD+hd]
    f16* Og = O + (size_t)(b * SEQ + q0 + w * 32) * DIM + h * HD;
#pragma unroll
    for (int mi = 0; mi < 2; ++mi)
#pragma unroll
        for (int r = 0; r < 4; ++r) {
            float inv = 1.0f / rsum[mi][r];
#pragma unroll
            for (int nh = 0; nh < 8; ++nh)
                Og[(size_t)(mi * 16 + lk * 4 + r) * DIM + nh * 16 + lrow] =
                    (f16)(oacc[mi][nh][r] * inv);
        }
}

extern "C" void kernel_launch(void* const* d_in, const int* in_sizes, int n_in,
                              void* d_out, int out_size, void* d_ws, size_t ws_size,
                              hipStream_t stream) {
    const float* x  = (const float*)d_in[0];
    const float* fc = (const float*)d_in[1];
    const float* fs = (const float*)d_in[2];
    // d_in[3] = mask: ignored, causal mask applied analytically.
    const float* wq = (const float*)d_in[4];
    const float* wk = (const float*)d_in[5];
    const float* wv = (const float*)d_in[6];
    const float* wo = (const float*)d_in[7];

    char* ws = (char*)d_ws;
    f16* x16  = (f16*)(ws);                              // 32 MiB; reused as attn out
    f16* wT   = (f16*)(ws + (size_t)32 * 1024 * 1024);   // 32 MiB, reused per weight
    f16* q16  = (f16*)(ws + (size_t)64 * 1024 * 1024);
    f16* k16  = (f16*)(ws + (size_t)96 * 1024 * 1024);
    f16* vT16 = (f16*)(ws + (size_t)128 * 1024 * 1024);  // ends at 160 MiB

    cvt_x_kernel<<<8192, 256, 0, stream>>>(x, x16);

    cvt_wT_kernel<<<dim3(64, 64), 256, 0, stream>>>(wq, wT);
    gemm_kernel<0><<<1024, 256, 0, stream>>>(x16, wT, q16, fc, fs);

    cvt_wT_kernel<<<dim3(64, 64), 256, 0, stream>>>(wk, wT);
    gemm_kernel<0><<<1024, 256, 0, stream>>>(x16, wT, k16, fc, fs);

    cvt_wT_kernel<<<dim3(64, 64), 256, 0, stream>>>(wv, wT);
    gemm_kernel<1><<<1024, 256, 0, stream>>>(x16, wT, vT16, nullptr, nullptr);

    attn_kernel<<<dim3(16, 64), 256, 0, stream>>>(q16, k16, vT16, x16);

    cvt_wT_kernel<<<dim3(64, 64), 256, 0, stream>>>(wo, wT);
    gemm_kernel<2><<<1024, 256, 0, stream>>>(x16, wT, d_out, nullptr, nullptr);
}

// Round 3
// 1653.162 us; speedup vs baseline: 1.5641x; 1.5641x over previous
//
#include <hip/hip_runtime.h>

// LlamaAttentionFused: B=2, S=2048, D=4096, H=32, HD=128, fp32 in/out.
// fp16 MFMA (16x16x32), fp32 accumulation.
// GEMM: 128x128 tile, BK=64, 4 waves (2x2), 4x4 frags/wave,
// global_load_lds width=16 into LINEAR LDS with pre-swizzled SOURCE columns
// (involution j ^= row&7 on 16B granules) + swizzled frag reads -> 2-way banks.
// ws layout (160 MiB):
//   [0,32M)    x16  (fp16 x)   -- reused as attention output
//   [32,64M)   wT   (fp16 transposed weight, reused per weight)
//   [64,96M)   q16  (post-RoPE Q)   [96,128M) k16   [128,160M) vT16

typedef _Float16 f16;
typedef _Float16 f16x8 __attribute__((ext_vector_type(8)));
typedef _Float16 f16x4 __attribute__((ext_vector_type(4)));
typedef float    f32x4 __attribute__((ext_vector_type(4)));

#define MFMA16(a, b, c) __builtin_amdgcn_mfma_f32_16x16x32_f16(a, b, c, 0, 0, 0)

#define GLOAD16(gp, lp)                                                        \
    __builtin_amdgcn_global_load_lds(                                          \
        (const __attribute__((address_space(1))) void*)(uintptr_t)(gp),        \
        (__attribute__((address_space(3))) void*)(uint32_t)(uintptr_t)(lp),    \
        16, 0, 0)

constexpr int SEQ = 2048, DIM = 4096, NH = 32, HD = 128;

// ---------------- x fp32 -> fp16 ----------------
__global__ void cvt_x_kernel(const float* __restrict__ x, f16* __restrict__ o) {
    int i = blockIdx.x * blockDim.x + threadIdx.x;
    const float4* p = (const float4*)x;
    float4 a = p[2 * i], b = p[2 * i + 1];
    f16x8 v = {(f16)a.x, (f16)a.y, (f16)a.z, (f16)a.w,
               (f16)b.x, (f16)b.y, (f16)b.z, (f16)b.w};
    ((f16x8*)o)[i] = v;
}

// ------------- w [K][N] f32 -> wT [N][K] f16 -------------
__global__ void cvt_wT_kernel(const float* __restrict__ w, f16* __restrict__ wT) {
    __shared__ float t[64][65];
    const int c0 = blockIdx.x * 64, r0 = blockIdx.y * 64;
    const int tr = threadIdx.x >> 4, tc = threadIdx.x & 15;
#pragma unroll
    for (int p = 0; p < 4; ++p) {
        int r = p * 16 + tr;
        float4 v = *(const float4*)&w[(size_t)(r0 + r) * DIM + c0 + tc * 4];
        t[tc * 4 + 0][r] = v.x; t[tc * 4 + 1][r] = v.y;
        t[tc * 4 + 2][r] = v.z; t[tc * 4 + 3][r] = v.w;
    }
    __syncthreads();
#pragma unroll
    for (int p = 0; p < 4; ++p) {
        int n = p * 16 + tr;
        f16x4 v = {(f16)t[n][tc * 4 + 0], (f16)t[n][tc * 4 + 1],
                   (f16)t[n][tc * 4 + 2], (f16)t[n][tc * 4 + 3]};
        *(f16x4*)&wT[(size_t)(c0 + n) * DIM + r0 + tc * 4] = v;
    }
}

// ---------------- GEMM: C = A * BT^T ----------------
// EPI: 0 = RoPE fp16 out, 1 = per-head V-transpose fp16 out, 2 = fp32 out.
union GemmLds {
    struct { f16 As[128][64]; f16 Bs[128][64]; } st;  // 32 KiB, linear dest, swizzled contents
    float C[64][133];                                  // 34 KiB epilogue bounce
};

template <int EPI>
__launch_bounds__(256, 3)
__global__ void gemm_kernel(const f16* __restrict__ A, const f16* __restrict__ BT,
                            void* __restrict__ OutP,
                            const float* __restrict__ fc, const float* __restrict__ fs) {
    __shared__ GemmLds lds;
    // XCD-aware bijective swizzle: 1024 blocks, 1024 % 8 == 0.
    const int bid = blockIdx.x;
    const int swz = (bid & 7) * 128 + (bid >> 3);
    const int n0 = (swz & 31) * 128, m0 = (swz >> 5) * 128;
    const int tid = threadIdx.x;
    const int lane = tid & 63, w = tid >> 6;
    const int wr = w >> 1, wc = w & 1;           // wave grid 2x2
    const int lrow = lane & 15, lk = lane >> 4;  // frag row, k-group

    // Staging: granule g = q*256 + tid (16B each); row = g>>3 = q*32 + (tid>>3),
    // dest granule-in-row jdst = tid&7 (LINEAR). Source column granule
    // jsrc = jdst ^ (row&7) = (tid&7) ^ ((tid>>3)&7)  (issue-invariant: q*32 ≡ 0 mod 8).
    const int srow = tid >> 3;
    const int jsrc = (tid & 7) ^ (srow & 7);
    const f16* gA = A + (size_t)(m0 + srow) * DIM + jsrc * 8;
    const f16* gB = BT + (size_t)(n0 + srow) * DIM + jsrc * 8;
    f16* lA = &lds.st.As[0][0] + w * 512;   // wave-uniform base (w*1024 B)
    f16* lB = &lds.st.Bs[0][0] + w * 512;

    f32x4 acc[4][4] = {};

    for (int k0 = 0; k0 < DIM; k0 += 64) {
        __syncthreads();  // all waves done reading previous tile
#pragma unroll
        for (int q = 0; q < 4; ++q) {
            GLOAD16(gA + k0 + (size_t)(q * 32) * DIM, lA + q * 2048);
            GLOAD16(gB + k0 + (size_t)(q * 32) * DIM, lB + q * 2048);
        }
        __syncthreads();  // drains vmcnt: tile visible

#pragma unroll
        for (int ks = 0; ks < 2; ++ks) {
            f16x8 af[4];
#pragma unroll
            for (int i = 0; i < 4; ++i) {
                int row = wr * 64 + i * 16 + lrow;
                int gidx = (ks * 4 + lk) ^ (lrow & 7);   // swizzled read
                af[i] = *(const f16x8*)&lds.st.As[row][gidx * 8];
            }
#pragma unroll
            for (int j = 0; j < 4; ++j) {
                int row = wc * 64 + j * 16 + lrow;
                int gidx = (ks * 4 + lk) ^ (lrow & 7);
                f16x8 bf = *(const f16x8*)&lds.st.Bs[row][gidx * 8];
#pragma unroll
                for (int i = 0; i < 4; ++i)
                    acc[i][j] = MFMA16(af[i], bf, acc[i][j]);
            }
        }
    }

    if constexpr (EPI == 2) {  // fp32 direct store (final @ wo)
        float* Out = (float*)OutP;
#pragma unroll
        for (int i = 0; i < 4; ++i)
#pragma unroll
            for (int j = 0; j < 4; ++j)
#pragma unroll
                for (int r = 0; r < 4; ++r)
                    Out[(size_t)(m0 + wr * 64 + i * 16 + lk * 4 + r) * DIM +
                        n0 + wc * 64 + j * 16 + lrow] = acc[i][j][r];
        return;
    }

    // LDS-bounce epilogues, 64 output rows per pass
    for (int pass = 0; pass < 2; ++pass) {
        __syncthreads();
        if (wr == pass) {
#pragma unroll
            for (int i = 0; i < 4; ++i)
#pragma unroll
                for (int j = 0; j < 4; ++j)
#pragma unroll
                    for (int r = 0; r < 4; ++r)
                        lds.C[i * 16 + lk * 4 + r][wc * 64 + j * 16 + lrow] = acc[i][j][r];
        }
        __syncthreads();
        const int rowbase = m0 + pass * 64;
        if constexpr (EPI == 0) {  // RoPE: N-tile 128 spans exactly one head
            f16* Out = (f16*)OutP;
            for (int it = 0; it < 16; ++it) {
                int idx = it * 256 + tid;
                int r = idx >> 6, p = idx & 63;
                int s = (rowbase + r) & (SEQ - 1);
                float x1 = lds.C[r][p], x2 = lds.C[r][p + 64];
                float c = fc[s * 64 + p], sn = fs[s * 64 + p];
                f16* o = Out + (size_t)(rowbase + r) * DIM + n0;
                o[p]      = (f16)(x1 * c - x2 * sn);
                o[p + 64] = (f16)(x1 * sn + x2 * c);
            }
        } else {  // EPI == 1: V transpose per head -> [(b*NH+h)*HD + hd][SEQ]
            f16* Out = (f16*)OutP;
            const int b = rowbase >> 11, h = n0 >> 7, sbase = rowbase & (SEQ - 1);
            f16* o = Out + ((size_t)(b * NH + h) * HD) * SEQ + sbase;
            for (int rep = 0; rep < 32; ++rep) {
                int hd = rep * 4 + w;
                o[(size_t)hd * SEQ + lane] = (f16)lds.C[lane][hd];
            }
        }
    }
}

// ---------------- Flash attention (causal), fp16 MFMA, fp32 softmax ----------------
union AttnLds {
    f16 Qs[128][136];
    struct { f16 Ks[64][136]; f16 Vs[128][72]; f16 Ps[4][32][72]; } st;
};

__launch_bounds__(256, 2)
__global__ void attn_kernel(const f16* __restrict__ Q, const f16* __restrict__ K,
                            const f16* __restrict__ VT, f16* __restrict__ O) {
    __shared__ AttnLds lds;
    constexpr float SCALE = 0.08838834764831843f;  // 1/sqrt(128)
    const int q0 = blockIdx.x * 128;
    const int bh = blockIdx.y, b = bh >> 5, h = bh & 31;
    const int tid = threadIdx.x, lane = tid & 63, w = tid >> 6;
    const int lrow = lane & 15, lk = lane >> 4;

    const f16* Qg = Q + (size_t)(b * SEQ + q0) * DIM + h * HD;
    const f16* Kg = K + (size_t)(b * SEQ) * DIM + h * HD;
    const f16* Vg = VT + (size_t)bh * HD * SEQ;

    {  // stage Q tile 128x128
        int r = tid >> 4, c8 = (tid & 15) * 8;
#pragma unroll
        for (int p = 0; p < 8; ++p)
            *(f16x8*)&lds.Qs[p * 16 + r][c8] = *(const f16x8*)&Qg[(size_t)(p * 16 + r) * DIM + c8];
    }
    __syncthreads();
    f16x8 qf[2][4];
#pragma unroll
    for (int mi = 0; mi < 2; ++mi)
#pragma unroll
        for (int ks = 0; ks < 4; ++ks)
            qf[mi][ks] = *(const f16x8*)&lds.Qs[w * 32 + mi * 16 + lrow][ks * 32 + lk * 8];

    f32x4 oacc[2][8] = {};
    float rmax[2][4], rsum[2][4];
#pragma unroll
    for (int mi = 0; mi < 2; ++mi)
#pragma unroll
        for (int r = 0; r < 4; ++r) { rmax[mi][r] = -3.0e38f; rsum[mi][r] = 0.f; }

    const int nkv = (q0 >> 6) + 2;
    for (int kv = 0; kv < nkv; ++kv) {
        __syncthreads();
        {
            int r = tid >> 4, c8 = (tid & 15) * 8;
#pragma unroll
            for (int p = 0; p < 4; ++p)
                *(f16x8*)&lds.st.Ks[p * 16 + r][c8] =
                    *(const f16x8*)&Kg[(size_t)(kv * 64 + p * 16 + r) * DIM + c8];
            int vr = tid >> 3, vc8 = (tid & 7) * 8;
#pragma unroll
            for (int p = 0; p < 4; ++p)
                *(f16x8*)&lds.st.Vs[p * 32 + vr][vc8] =
                    *(const f16x8*)&Vg[(size_t)(p * 32 + vr) * SEQ + kv * 64 + vc8];
        }
        __syncthreads();

        f32x4 sacc[2][4] = {};
#pragma unroll
        for (int nj = 0; nj < 4; ++nj)
#pragma unroll
            for (int ks = 0; ks < 4; ++ks) {
                f16x8 kf = *(const f16x8*)&lds.st.Ks[nj * 16 + lrow][ks * 32 + lk * 8];
                sacc[0][nj] = MFMA16(qf[0][ks], kf, sacc[0][nj]);
                sacc[1][nj] = MFMA16(qf[1][ks], kf, sacc[1][nj]);
            }

        const bool need_mask = (kv * 64 + 63) > q0;
#pragma unroll
        for (int mi = 0; mi < 2; ++mi)
#pragma unroll
            for (int r = 0; r < 4; ++r) {
                float tm = -3.0e38f;
#pragma unroll
                for (int nj = 0; nj < 4; ++nj) {
                    float v = sacc[mi][nj][r] * SCALE;
                    if (need_mask) {
                        int row = q0 + w * 32 + mi * 16 + lk * 4 + r;
                        int col = kv * 64 + nj * 16 + lrow;
                        if (col > row) v = -3.0e38f;
                    }
                    sacc[mi][nj][r] = v;
                    tm = fmaxf(tm, v);
                }
#pragma unroll
                for (int off = 1; off < 16; off <<= 1)
                    tm = fmaxf(tm, __shfl_xor(tm, off, 64));
                float mnew = fmaxf(rmax[mi][r], tm);
                float fac = __expf(rmax[mi][r] - mnew);
                rmax[mi][r] = mnew;
                rsum[mi][r] *= fac;
#pragma unroll
                for (int nh = 0; nh < 8; ++nh) oacc[mi][nh][r] *= fac;
                float ps = 0.f;
#pragma unroll
                for (int nj = 0; nj < 4; ++nj) {
                    float p = __expf(sacc[mi][nj][r] - mnew);
                    sacc[mi][nj][r] = p;
                    ps += p;
                }
#pragma unroll
                for (int off = 1; off < 16; off <<= 1)
                    ps += __shfl_xor(ps, off, 64);
                rsum[mi][r] += ps;
            }

#pragma unroll
        for (int mi = 0; mi < 2; ++mi)
#pragma unroll
            for (int nj = 0; nj < 4; ++nj)
#pragma unroll
                for (int r = 0; r < 4; ++r)
                    lds.st.Ps[w][mi * 16 + lk * 4 + r][nj * 16 + lrow] = (f16)sacc[mi][nj][r];
        asm volatile("s_waitcnt lgkmcnt(0)" ::: "memory");
        __builtin_amdgcn_sched_barrier(0);

#pragma unroll
        for (int ks = 0; ks < 2; ++ks) {
            f16x8 pf0 = *(const f16x8*)&lds.st.Ps[w][lrow][ks * 32 + lk * 8];
            f16x8 pf1 = *(const f16x8*)&lds.st.Ps[w][16 + lrow][ks * 32 + lk * 8];
#pragma unroll
            for (int nh = 0; nh < 8; ++nh) {
                f16x8 vf = *(const f16x8*)&lds.st.Vs[nh * 16 + lrow][ks * 32 + lk * 8];
                oacc[0][nh] = MFMA16(pf0, vf, oacc[0][nh]);
                oacc[1][nh] = MFMA16(pf1, vf, oacc[1][nh]);
            }
        }
    }

    f16* Og = O + (size_t)(b * SEQ + q0 + w * 32) * DIM + h * HD;
#pragma unroll
    for (int mi = 0; mi < 2; ++mi)
#pragma unroll
        for (int r = 0; r < 4; ++r) {
            float inv = 1.0f / rsum[mi][r];
#pragma unroll
            for (int nh = 0; nh < 8; ++nh)
                Og[(size_t)(mi * 16 + lk * 4 + r) * DIM + nh * 16 + lrow] =
                    (f16)(oacc[mi][nh][r] * inv);
        }
}

extern "C" void kernel_launch(void* const* d_in, const int* in_sizes, int n_in,
                              void* d_out, int out_size, void* d_ws, size_t ws_size,
                              hipStream_t stream) {
    const float* x  = (const float*)d_in[0];
    const float* fc = (const float*)d_in[1];
    const float* fs = (const float*)d_in[2];
    // d_in[3] = mask: ignored (causal mask applied analytically).
    const float* wq = (const float*)d_in[4];
    const float* wk = (const float*)d_in[5];
    const float* wv = (const float*)d_in[6];
    const float* wo = (const float*)d_in[7];

    char* ws = (char*)d_ws;
    f16* x16  = (f16*)(ws);
    f16* wT   = (f16*)(ws + (size_t)32 * 1024 * 1024);
    f16* q16  = (f16*)(ws + (size_t)64 * 1024 * 1024);
    f16* k16  = (f16*)(ws + (size_t)96 * 1024 * 1024);
    f16* vT16 = (f16*)(ws + (size_t)128 * 1024 * 1024);

    cvt_x_kernel<<<8192, 256, 0, stream>>>(x, x16);

    cvt_wT_kernel<<<dim3(64, 64), 256, 0, stream>>>(wq, wT);
    gemm_kernel<0><<<1024, 256, 0, stream>>>(x16, wT, q16, fc, fs);

    cvt_wT_kernel<<<dim3(64, 64), 256, 0, stream>>>(wk, wT);
    gemm_kernel<0><<<1024, 256, 0, stream>>>(x16, wT, k16, fc, fs);

    cvt_wT_kernel<<<dim3(64, 64), 256, 0, stream>>>(wv, wT);
    gemm_kernel<1><<<1024, 256, 0, stream>>>(x16, wT, vT16, nullptr, nullptr);

    attn_kernel<<<dim3(16, 64), 256, 0, stream>>>(q16, k16, vT16, x16);

    cvt_wT_kernel<<<dim3(64, 64), 256, 0, stream>>>(wo, wT);
    gemm_kernel<2><<<1024, 256, 0, stream>>>(x16, wT, d_out, nullptr, nullptr);
}